// Round 1
// baseline (98.762 us; speedup 1.0000x reference)
//
#include <hip/hip_runtime.h>
#include <math.h>

#define N_G    512
#define IMG_H  256
#define IMG_W  256
#define NPARAM 9
// param rows in ws/LDS: 0 px, 1 py, 2 conA, 3 conB, 4 conC, 5 op, 6 cr, 7 cg, 8 cb

__global__ __launch_bounds__(512) void gs_preprocess_sort(
    const float* __restrict__ means3D,
    const float* __restrict__ opacities,
    const float* __restrict__ colors,
    const float* __restrict__ scales,
    const float* __restrict__ rotations,
    const float* __restrict__ viewmatrix,
    const float* __restrict__ projmatrix,
    float* __restrict__ ws,        // [NPARAM][N_G] depth-sorted
    float* __restrict__ radii_out) // N_G floats (d_out tail)
{
    __shared__ float sp[NPARAM][N_G];
    __shared__ float skey[N_G];
    __shared__ int   sidx[N_G];
    const int g = threadIdx.x;

    float VM[16], PM[16];
    #pragma unroll
    for (int i = 0; i < 16; ++i) { VM[i] = viewmatrix[i]; PM[i] = projmatrix[i]; }

    const float mx = means3D[g*3+0], my = means3D[g*3+1], mz = means3D[g*3+2];
    float rq = rotations[g*4+0], xq = rotations[g*4+1], yq = rotations[g*4+2], zq = rotations[g*4+3];
    const float qn = sqrtf(rq*rq + xq*xq + yq*yq + zq*zq);
    rq /= qn; xq /= qn; yq /= qn; zq /= qn;
    const float R00 = 1.f - 2.f*(yq*yq + zq*zq);
    const float R01 = 2.f*(xq*yq - rq*zq);
    const float R02 = 2.f*(xq*zq + rq*yq);
    const float R10 = 2.f*(xq*yq + rq*zq);
    const float R11 = 1.f - 2.f*(xq*xq + zq*zq);
    const float R12 = 2.f*(yq*zq - rq*xq);
    const float R20 = 2.f*(xq*zq - rq*yq);
    const float R21 = 2.f*(yq*zq + rq*xq);
    const float R22 = 1.f - 2.f*(xq*xq + yq*yq);
    float s0 = scales[g*3+0], s1 = scales[g*3+1], s2 = scales[g*3+2];
    s0 *= s0; s1 *= s1; s2 *= s2;
    // Sigma = R diag(s) R^T (symmetric)
    const float S00 = R00*R00*s0 + R01*R01*s1 + R02*R02*s2;
    const float S01 = R00*R10*s0 + R01*R11*s1 + R02*R12*s2;
    const float S02 = R00*R20*s0 + R01*R21*s1 + R02*R22*s2;
    const float S11 = R10*R10*s0 + R11*R11*s1 + R12*R12*s2;
    const float S12 = R10*R20*s0 + R11*R21*s1 + R12*R22*s2;
    const float S22 = R20*R20*s0 + R21*R21*s1 + R22*R22*s2;

    const float pv0 = VM[0]*mx + VM[1]*my + VM[2]*mz  + VM[3];
    const float pv1 = VM[4]*mx + VM[5]*my + VM[6]*mz  + VM[7];
    const float tz  = VM[8]*mx + VM[9]*my + VM[10]*mz + VM[11];
    const float FX = 256.f, FY = 256.f, limx = 0.65f, limy = 0.65f;
    const float tx = fminf(fmaxf(pv0/tz, -limx), limx) * tz;
    const float ty = fminf(fmaxf(pv1/tz, -limy), limy) * tz;
    const float itz = 1.f / tz, itz2 = itz*itz;
    const float J00 = FX*itz, J02 = -FX*tx*itz2;
    const float J11 = FY*itz, J12 = -FY*ty*itz2;
    // Tm = J @ VM[:3,:3]
    const float T00 = J00*VM[0] + J02*VM[8];
    const float T01 = J00*VM[1] + J02*VM[9];
    const float T02 = J00*VM[2] + J02*VM[10];
    const float T10 = J11*VM[4] + J12*VM[8];
    const float T11 = J11*VM[5] + J12*VM[9];
    const float T12 = J11*VM[6] + J12*VM[10];
    // cov2d = Tm Sigma Tm^T
    const float u0 = T00*S00 + T01*S01 + T02*S02;
    const float u1 = T00*S01 + T01*S11 + T02*S12;
    const float u2 = T00*S02 + T01*S12 + T02*S22;
    const float v0 = T10*S00 + T11*S01 + T12*S02;
    const float v1 = T10*S01 + T11*S11 + T12*S12;
    const float v2 = T10*S02 + T11*S12 + T12*S22;
    const float c00 = u0*T00 + u1*T01 + u2*T02;
    const float c01 = u0*T10 + u1*T11 + u2*T12;
    const float c11 = v0*T10 + v1*T11 + v2*T12;
    const float a = c00 + 0.3f, b = c01, c = c11 + 0.3f;
    const float det = a*c - b*b;
    const float inv_det = 1.f/det;
    float conA = c*inv_det, conB = -b*inv_det, conC = a*inv_det;
    const float ph0 = PM[0]*mx  + PM[1]*my  + PM[2]*mz  + PM[3];
    const float ph1 = PM[4]*mx  + PM[5]*my  + PM[6]*mz  + PM[7];
    const float ph3 = PM[12]*mx + PM[13]*my + PM[14]*mz + PM[15];
    const float pw = 1.f/(ph3 + 1e-7f);
    float pix_x = ((ph0*pw + 1.f)*(float)IMG_W - 1.f)*0.5f;
    float pix_y = ((ph1*pw + 1.f)*(float)IMG_H - 1.f)*0.5f;
    const float mid = 0.5f*(a + c);
    const float lam = mid + sqrtf(fmaxf(0.1f, mid*mid - det));
    const bool valid = (tz > 0.2f) && (det > 0.f);
    radii_out[g] = valid ? ceilf(3.f*sqrtf(lam)) : 0.f;

    float op = opacities[g];
    if (!valid) { conA = conB = conC = 0.f; op = 0.f; pix_x = 0.f; pix_y = 0.f; }
    sp[0][g] = pix_x; sp[1][g] = pix_y;
    sp[2][g] = conA;  sp[3][g] = conB;  sp[4][g] = conC;
    sp[5][g] = op;
    sp[6][g] = colors[g*3+0]; sp[7][g] = colors[g*3+1]; sp[8][g] = colors[g*3+2];
    skey[g] = tz; sidx[g] = g;
    __syncthreads();

    // bitonic ascending sort on (tz, idx) — matches stable argsort
    for (int k = 2; k <= N_G; k <<= 1) {
        for (int j = k >> 1; j > 0; j >>= 1) {
            const int ixj = g ^ j;
            if (ixj > g) {
                const float k0 = skey[g], k1 = skey[ixj];
                const int   i0 = sidx[g], i1 = sidx[ixj];
                const bool gt = (k0 > k1) || (k0 == k1 && i0 > i1);
                const bool up = ((g & k) == 0);
                if (gt == up) { skey[g]=k1; skey[ixj]=k0; sidx[g]=i1; sidx[ixj]=i0; }
            }
            __syncthreads();
        }
    }
    const int src = sidx[g];
    #pragma unroll
    for (int p = 0; p < NPARAM; ++p)
        ws[p*N_G + g] = sp[p][src];
}

__global__ __launch_bounds__(256) void gs_rasterize(
    const float* __restrict__ ws,  // [NPARAM][N_G] depth-sorted
    const float* __restrict__ bg,
    float* __restrict__ img)       // [3][IMG_H][IMG_W]
{
    __shared__ float sp[NPARAM][N_G];
    const int tid = threadIdx.x;
    #pragma unroll
    for (int k = tid; k < NPARAM*N_G; k += 256)
        (&sp[0][0])[k] = ws[k];
    __syncthreads();

    const int tilex = blockIdx.x & 15, tiley = blockIdx.x >> 4;
    const int px = (tilex << 4) + (tid & 15);
    const int py = (tiley << 4) + (tid >> 4);
    const float fx = (float)px, fy = (float)py;

    float T = 1.f, cr = 0.f, cg = 0.f, cb = 0.f;
    for (int i = 0; i < N_G; ++i) {
        const float dx = sp[0][i] - fx;
        const float dy = sp[1][i] - fy;
        const float A = sp[2][i], B = sp[3][i], C = sp[4][i];
        const float power = -0.5f*(A*dx*dx + C*dy*dy) - B*dx*dy;
        const float al = fminf(0.99f, sp[5][i]*__expf(power));
        if (power > 0.f || al < (1.0f/255.0f)) continue;
        const float Tnew = T * (1.f - al);
        if (Tnew < 1e-4f) { T = Tnew; break; }  // gate off; all later weights are 0 too
        const float w = al * T;
        cr += w * sp[6][i];
        cg += w * sp[7][i];
        cb += w * sp[8][i];
        T = Tnew;
    }
    const int pix = py*IMG_W + px;
    img[pix]                       = cr + T*bg[0];
    img[IMG_H*IMG_W + pix]         = cg + T*bg[1];
    img[2*IMG_H*IMG_W + pix]       = cb + T*bg[2];
}

extern "C" void kernel_launch(void* const* d_in, const int* in_sizes, int n_in,
                              void* d_out, int out_size, void* d_ws, size_t ws_size,
                              hipStream_t stream) {
    const float* means3D    = (const float*)d_in[0];
    // d_in[1] = means2D (unused by reference math)
    const float* opacities  = (const float*)d_in[2];
    const float* colors     = (const float*)d_in[3];
    const float* scales     = (const float*)d_in[4];
    const float* rotations  = (const float*)d_in[5];
    const float* viewmatrix = (const float*)d_in[6];
    const float* projmatrix = (const float*)d_in[7];
    const float* bg         = (const float*)d_in[8];

    float* img   = (float*)d_out;                       // 3*256*256
    float* radii = (float*)d_out + 3*IMG_H*IMG_W;       // 512 (as float values)
    float* ws    = (float*)d_ws;                        // NPARAM*N_G floats

    gs_preprocess_sort<<<1, N_G, 0, stream>>>(means3D, opacities, colors, scales,
                                              rotations, viewmatrix, projmatrix,
                                              ws, radii);
    gs_rasterize<<<(IMG_H/16)*(IMG_W/16), 256, 0, stream>>>(ws, bg, img);
}

// Round 2
// 46.580 us; speedup vs baseline: 2.1203x; 2.1203x over previous
//
#include <hip/hip_runtime.h>
#include <math.h>

#define N_G    512
#define IMG_H  256
#define IMG_W  256

// Fully fused: per-block (= per 16x16 tile) preprocess of all 512 gaussians,
// O(N) stable counting-rank by depth, local tile-coverage bitmask, then
// front-to-back alpha blend over only the covering gaussians.
__global__ __launch_bounds__(256) void gs_fused(
    const float* __restrict__ means3D,
    const float* __restrict__ opacities,
    const float* __restrict__ colors,
    const float* __restrict__ scales,
    const float* __restrict__ rotations,
    const float* __restrict__ viewmatrix,
    const float* __restrict__ projmatrix,
    const float* __restrict__ bg,
    float* __restrict__ img,        // [3][IMG_H][IMG_W]
    float* __restrict__ radii_out)  // N_G floats (original order)
{
    __shared__ float sp[9][N_G];        // 0 px,1 py,2 A,3 B,4 C,5 op,6 cr,7 cg,8 cb
    __shared__ float skey[N_G];         // tz depth keys
    __shared__ int   sortedIdx[N_G];    // rank -> original gaussian
    __shared__ unsigned int tmask[N_G / 32];

    const int tid = threadIdx.x;
    const int bx = blockIdx.x & 15, by = blockIdx.x >> 4;

    if (tid < N_G / 32) tmask[tid] = 0u;

    float VM[16], PM[16];
    #pragma unroll
    for (int i = 0; i < 16; ++i) { VM[i] = viewmatrix[i]; PM[i] = projmatrix[i]; }

    // ---- Phase 1: per-gaussian preprocess (each thread owns g = tid, tid+256)
    float g_px[2], g_py[2], g_r[2], g_key[2];
    #pragma unroll
    for (int gi = 0; gi < 2; ++gi) {
        const int g = tid + gi * 256;
        const float mx = means3D[g*3+0], my = means3D[g*3+1], mz = means3D[g*3+2];
        float rq = rotations[g*4+0], xq = rotations[g*4+1], yq = rotations[g*4+2], zq = rotations[g*4+3];
        const float qn = sqrtf(rq*rq + xq*xq + yq*yq + zq*zq);
        rq /= qn; xq /= qn; yq /= qn; zq /= qn;
        const float R00 = 1.f - 2.f*(yq*yq + zq*zq);
        const float R01 = 2.f*(xq*yq - rq*zq);
        const float R02 = 2.f*(xq*zq + rq*yq);
        const float R10 = 2.f*(xq*yq + rq*zq);
        const float R11 = 1.f - 2.f*(xq*xq + zq*zq);
        const float R12 = 2.f*(yq*zq - rq*xq);
        const float R20 = 2.f*(xq*zq - rq*yq);
        const float R21 = 2.f*(yq*zq + rq*xq);
        const float R22 = 1.f - 2.f*(xq*xq + yq*yq);
        float s0 = scales[g*3+0], s1 = scales[g*3+1], s2 = scales[g*3+2];
        s0 *= s0; s1 *= s1; s2 *= s2;
        const float S00 = R00*R00*s0 + R01*R01*s1 + R02*R02*s2;
        const float S01 = R00*R10*s0 + R01*R11*s1 + R02*R12*s2;
        const float S02 = R00*R20*s0 + R01*R21*s1 + R02*R22*s2;
        const float S11 = R10*R10*s0 + R11*R11*s1 + R12*R12*s2;
        const float S12 = R10*R20*s0 + R11*R21*s1 + R12*R22*s2;
        const float S22 = R20*R20*s0 + R21*R21*s1 + R22*R22*s2;

        const float pv0 = VM[0]*mx + VM[1]*my + VM[2]*mz  + VM[3];
        const float pv1 = VM[4]*mx + VM[5]*my + VM[6]*mz  + VM[7];
        const float tz  = VM[8]*mx + VM[9]*my + VM[10]*mz + VM[11];
        const float FX = 256.f, FY = 256.f, limx = 0.65f, limy = 0.65f;
        const float tx = fminf(fmaxf(pv0/tz, -limx), limx) * tz;
        const float ty = fminf(fmaxf(pv1/tz, -limy), limy) * tz;
        const float itz = 1.f / tz, itz2 = itz*itz;
        const float J00 = FX*itz, J02 = -FX*tx*itz2;
        const float J11 = FY*itz, J12 = -FY*ty*itz2;
        const float T00 = J00*VM[0] + J02*VM[8];
        const float T01 = J00*VM[1] + J02*VM[9];
        const float T02 = J00*VM[2] + J02*VM[10];
        const float T10 = J11*VM[4] + J12*VM[8];
        const float T11 = J11*VM[5] + J12*VM[9];
        const float T12 = J11*VM[6] + J12*VM[10];
        const float u0 = T00*S00 + T01*S01 + T02*S02;
        const float u1 = T00*S01 + T01*S11 + T02*S12;
        const float u2 = T00*S02 + T01*S12 + T02*S22;
        const float v0 = T10*S00 + T11*S01 + T12*S02;
        const float v1 = T10*S01 + T11*S11 + T12*S12;
        const float v2 = T10*S02 + T11*S12 + T12*S22;
        const float c00 = u0*T00 + u1*T01 + u2*T02;
        const float c01 = u0*T10 + u1*T11 + u2*T12;
        const float c11 = v0*T10 + v1*T11 + v2*T12;
        const float a = c00 + 0.3f, b = c01, c = c11 + 0.3f;
        const float det = a*c - b*b;
        const float inv_det = 1.f/det;
        float conA = c*inv_det, conB = -b*inv_det, conC = a*inv_det;
        const float ph0 = PM[0]*mx  + PM[1]*my  + PM[2]*mz  + PM[3];
        const float ph1 = PM[4]*mx  + PM[5]*my  + PM[6]*mz  + PM[7];
        const float ph3 = PM[12]*mx + PM[13]*my + PM[14]*mz + PM[15];
        const float pw = 1.f/(ph3 + 1e-7f);
        const float pix_x = ((ph0*pw + 1.f)*(float)IMG_W - 1.f)*0.5f;
        const float pix_y = ((ph1*pw + 1.f)*(float)IMG_H - 1.f)*0.5f;
        const float mid = 0.5f*(a + c);
        const float lam = mid + sqrtf(fmaxf(0.1f, mid*mid - det));
        const bool valid = (tz > 0.2f) && (det > 0.f);
        float op = opacities[g];
        if (!valid) { conA = conB = conC = 0.f; op = 0.f; }

        sp[0][g] = pix_x; sp[1][g] = pix_y;
        sp[2][g] = conA;  sp[3][g] = conB;  sp[4][g] = conC;
        sp[5][g] = op;
        sp[6][g] = colors[g*3+0]; sp[7][g] = colors[g*3+1]; sp[8][g] = colors[g*3+2];
        skey[g] = tz;
        g_px[gi] = pix_x; g_py[gi] = pix_y; g_key[gi] = tz;
        // Exact conservative cull radius: contribution needs
        // op*exp(-|d|^2/(2*lam)) >= 1/255  =>  |d|^2 <= 2*lam*ln(255*op).
        // (lam >= lambda_max of the regularized cov2d because the sqrt arg is
        //  clamped upward, so q >= |d|^2/lam — bound is provably conservative.)
        const bool cullable = valid && (op * 255.f > 1.f);
        g_r[gi] = cullable ? sqrtf(2.f * lam * logf(255.f * op)) + 0.01f : -1.f;

        if (blockIdx.x == 0)
            radii_out[g] = valid ? ceilf(3.f*sqrtf(lam)) : 0.f;
    }
    __syncthreads();

    // ---- Phase 2: stable counting-rank on (tz, idx) + local tile mask
    int g_rank[2];
    {
        const float k0 = g_key[0], k1 = g_key[1];
        int r0 = 0, r1 = 0;
        #pragma unroll 8
        for (int j = 0; j < N_G; ++j) {
            const float kj = skey[j];               // LDS broadcast (free)
            r0 += (kj < k0) || (kj == k0 && j < tid);
            r1 += (kj < k1) || (kj == k1 && j < tid + 256);
        }
        g_rank[0] = r0; g_rank[1] = r1;
    }
    {
        const float x0 = (float)(bx * 16), x1 = x0 + 15.f;
        const float y0 = (float)(by * 16), y1 = y0 + 15.f;
        #pragma unroll
        for (int gi = 0; gi < 2; ++gi) {
            const int rk = g_rank[gi];
            sortedIdx[rk] = tid + gi * 256;
            const float r = g_r[gi];
            if (r > 0.f &&
                g_px[gi] + r >= x0 && g_px[gi] - r <= x1 &&
                g_py[gi] + r >= y0 && g_py[gi] - r <= y1) {
                atomicOr(&tmask[rk >> 5], 1u << (rk & 31));
            }
        }
    }
    __syncthreads();

    // ---- Phase 3: front-to-back blend over covering gaussians only
    const int lx = tid & 15, ly = tid >> 4;
    const int px = bx * 16 + lx, py = by * 16 + ly;
    const float fx = (float)px, fy = (float)py;

    float T = 1.f, cr = 0.f, cg = 0.f, cb = 0.f;
    bool done = false;
    for (int w = 0; w < N_G / 32; ++w) {
        unsigned int bits = tmask[w];               // broadcast
        while (bits) {
            const int b = __builtin_ctz(bits);
            bits &= bits - 1;
            const int g = sortedIdx[w * 32 + b];    // broadcast
            const float dx = sp[0][g] - fx;
            const float dy = sp[1][g] - fy;
            const float A = sp[2][g], B = sp[3][g], C = sp[4][g];
            const float power = -0.5f*(A*dx*dx + C*dy*dy) - B*dx*dy;
            const float al = fminf(0.99f, sp[5][g]*__expf(power));
            if (!done && !(power > 0.f || al < (1.0f/255.0f))) {
                const float Tnew = T * (1.f - al);
                if (Tnew < 1e-4f) { T = Tnew; done = true; }
                else {
                    const float wgt = al * T;
                    cr += wgt * sp[6][g];
                    cg += wgt * sp[7][g];
                    cb += wgt * sp[8][g];
                    T = Tnew;
                }
            }
        }
        if (__all(done)) break;
    }
    const int pix = py * IMG_W + px;
    img[pix]                   = cr + T * bg[0];
    img[IMG_H*IMG_W   + pix]   = cg + T * bg[1];
    img[2*IMG_H*IMG_W + pix]   = cb + T * bg[2];
}

extern "C" void kernel_launch(void* const* d_in, const int* in_sizes, int n_in,
                              void* d_out, int out_size, void* d_ws, size_t ws_size,
                              hipStream_t stream) {
    const float* means3D    = (const float*)d_in[0];
    // d_in[1] = means2D (unused by reference math)
    const float* opacities  = (const float*)d_in[2];
    const float* colors     = (const float*)d_in[3];
    const float* scales     = (const float*)d_in[4];
    const float* rotations  = (const float*)d_in[5];
    const float* viewmatrix = (const float*)d_in[6];
    const float* projmatrix = (const float*)d_in[7];
    const float* bg         = (const float*)d_in[8];

    float* img   = (float*)d_out;                   // 3*256*256
    float* radii = (float*)d_out + 3*IMG_H*IMG_W;   // 512 (as float values)

    gs_fused<<<(IMG_H/16)*(IMG_W/16), 256, 0, stream>>>(
        means3D, opacities, colors, scales, rotations,
        viewmatrix, projmatrix, bg, img, radii);
}

// Round 3
// 45.284 us; speedup vs baseline: 2.1810x; 1.0286x over previous
//
#include <hip/hip_runtime.h>
#include <math.h>

#define N_G    512
#define IMG_H  256
#define IMG_W  256

// Fused tile rasterizer with depth-ordered compaction:
//  P1: per-block preprocess of all 512 gaussians -> sp[9][g], skey[g]
//  P2: O(N) stable counting-rank by (tz, idx); tile coverage bitmask by rank
//  P2.5: prefix-popcount compaction of covering gaussians into sequential
//        float4 LDS arrays (breaks the per-pixel indirect-LDS latency chain)
//  P3: front-to-back blend over the compact list, unrolled x8
__global__ __launch_bounds__(256) void gs_fused(
    const float* __restrict__ means3D,
    const float* __restrict__ opacities,
    const float* __restrict__ colors,
    const float* __restrict__ scales,
    const float* __restrict__ rotations,
    const float* __restrict__ viewmatrix,
    const float* __restrict__ projmatrix,
    const float* __restrict__ bg,
    float* __restrict__ img,        // [3][IMG_H][IMG_W]
    float* __restrict__ radii_out)  // N_G floats (original order)
{
    __shared__ float sp[9][N_G];        // 0 px,1 py,2 A,3 B,4 C,5 op,6 cr,7 cg,8 cb
    __shared__ float skey[N_G];
    __shared__ int   sortedIdx[N_G];    // rank -> original gaussian
    __shared__ unsigned int tmask[N_G / 32];
    __shared__ float4 c0[N_G];          // {px,py,A,B}   depth-ordered compact
    __shared__ float4 c1[N_G];          // {C,op,cr,cg}
    __shared__ float  c2[N_G];          // {cb}

    const int tid = threadIdx.x;
    const int bx = blockIdx.x & 15, by = blockIdx.x >> 4;

    if (tid < N_G / 32) tmask[tid] = 0u;

    float VM[16], PM[16];
    #pragma unroll
    for (int i = 0; i < 16; ++i) { VM[i] = viewmatrix[i]; PM[i] = projmatrix[i]; }

    // ---- Phase 1: preprocess (each thread owns g = tid, tid+256)
    float g_px[2], g_py[2], g_r[2], g_key[2];
    #pragma unroll
    for (int gi = 0; gi < 2; ++gi) {
        const int g = tid + gi * 256;
        const float mx = means3D[g*3+0], my = means3D[g*3+1], mz = means3D[g*3+2];
        float rq = rotations[g*4+0], xq = rotations[g*4+1], yq = rotations[g*4+2], zq = rotations[g*4+3];
        const float qn = sqrtf(rq*rq + xq*xq + yq*yq + zq*zq);
        rq /= qn; xq /= qn; yq /= qn; zq /= qn;
        const float R00 = 1.f - 2.f*(yq*yq + zq*zq);
        const float R01 = 2.f*(xq*yq - rq*zq);
        const float R02 = 2.f*(xq*zq + rq*yq);
        const float R10 = 2.f*(xq*yq + rq*zq);
        const float R11 = 1.f - 2.f*(xq*xq + zq*zq);
        const float R12 = 2.f*(yq*zq - rq*xq);
        const float R20 = 2.f*(xq*zq - rq*yq);
        const float R21 = 2.f*(yq*zq + rq*xq);
        const float R22 = 1.f - 2.f*(xq*xq + yq*yq);
        float s0 = scales[g*3+0], s1 = scales[g*3+1], s2 = scales[g*3+2];
        s0 *= s0; s1 *= s1; s2 *= s2;
        const float S00 = R00*R00*s0 + R01*R01*s1 + R02*R02*s2;
        const float S01 = R00*R10*s0 + R01*R11*s1 + R02*R12*s2;
        const float S02 = R00*R20*s0 + R01*R21*s1 + R02*R22*s2;
        const float S11 = R10*R10*s0 + R11*R11*s1 + R12*R12*s2;
        const float S12 = R10*R20*s0 + R11*R21*s1 + R12*R22*s2;
        const float S22 = R20*R20*s0 + R21*R21*s1 + R22*R22*s2;

        const float pv0 = VM[0]*mx + VM[1]*my + VM[2]*mz  + VM[3];
        const float pv1 = VM[4]*mx + VM[5]*my + VM[6]*mz  + VM[7];
        const float tz  = VM[8]*mx + VM[9]*my + VM[10]*mz + VM[11];
        const float FX = 256.f, FY = 256.f, limx = 0.65f, limy = 0.65f;
        const float tx = fminf(fmaxf(pv0/tz, -limx), limx) * tz;
        const float ty = fminf(fmaxf(pv1/tz, -limy), limy) * tz;
        const float itz = 1.f / tz, itz2 = itz*itz;
        const float J00 = FX*itz, J02 = -FX*tx*itz2;
        const float J11 = FY*itz, J12 = -FY*ty*itz2;
        const float T00 = J00*VM[0] + J02*VM[8];
        const float T01 = J00*VM[1] + J02*VM[9];
        const float T02 = J00*VM[2] + J02*VM[10];
        const float T10 = J11*VM[4] + J12*VM[8];
        const float T11 = J11*VM[5] + J12*VM[9];
        const float T12 = J11*VM[6] + J12*VM[10];
        const float u0 = T00*S00 + T01*S01 + T02*S02;
        const float u1 = T00*S01 + T01*S11 + T02*S12;
        const float u2 = T00*S02 + T01*S12 + T02*S22;
        const float v0 = T10*S00 + T11*S01 + T12*S02;
        const float v1 = T10*S01 + T11*S11 + T12*S12;
        const float v2 = T10*S02 + T11*S12 + T12*S22;
        const float c00 = u0*T00 + u1*T01 + u2*T02;
        const float c01 = u0*T10 + u1*T11 + u2*T12;
        const float c11 = v0*T10 + v1*T11 + v2*T12;
        const float a = c00 + 0.3f, b = c01, c = c11 + 0.3f;
        const float det = a*c - b*b;
        const float inv_det = 1.f/det;
        float conA = c*inv_det, conB = -b*inv_det, conC = a*inv_det;
        const float ph0 = PM[0]*mx  + PM[1]*my  + PM[2]*mz  + PM[3];
        const float ph1 = PM[4]*mx  + PM[5]*my  + PM[6]*mz  + PM[7];
        const float ph3 = PM[12]*mx + PM[13]*my + PM[14]*mz + PM[15];
        const float pw = 1.f/(ph3 + 1e-7f);
        const float pix_x = ((ph0*pw + 1.f)*(float)IMG_W - 1.f)*0.5f;
        const float pix_y = ((ph1*pw + 1.f)*(float)IMG_H - 1.f)*0.5f;
        const float mid = 0.5f*(a + c);
        const float lam = mid + sqrtf(fmaxf(0.1f, mid*mid - det));
        const bool valid = (tz > 0.2f) && (det > 0.f);
        float op = opacities[g];
        if (!valid) { conA = conB = conC = 0.f; op = 0.f; }

        sp[0][g] = pix_x; sp[1][g] = pix_y;
        sp[2][g] = conA;  sp[3][g] = conB;  sp[4][g] = conC;
        sp[5][g] = op;
        sp[6][g] = colors[g*3+0]; sp[7][g] = colors[g*3+1]; sp[8][g] = colors[g*3+2];
        skey[g] = tz;
        g_px[gi] = pix_x; g_py[gi] = pix_y; g_key[gi] = tz;
        // Conservative cull radius: op*exp(-|d|^2/(2*lam)) >= 1/255
        // => |d|^2 <= 2*lam*ln(255*op); lam >= lambda_max (sqrt arg clamped up).
        const bool cullable = valid && (op * 255.f > 1.f);
        g_r[gi] = cullable ? sqrtf(2.f * lam * logf(255.f * op)) + 0.01f : -1.f;

        if (blockIdx.x == 0)
            radii_out[g] = valid ? ceilf(3.f*sqrtf(lam)) : 0.f;
    }
    __syncthreads();

    // ---- Phase 2: stable counting-rank + tile mask (indexed by rank)
    int g_rank[2];
    {
        const float k0 = g_key[0], k1 = g_key[1];
        int r0 = 0, r1 = 0;
        #pragma unroll 8
        for (int j = 0; j < N_G; ++j) {
            const float kj = skey[j];               // LDS broadcast
            r0 += (kj < k0) || (kj == k0 && j < tid);
            r1 += (kj < k1) || (kj == k1 && j < tid + 256);
        }
        g_rank[0] = r0; g_rank[1] = r1;
    }
    {
        const float x0 = (float)(bx * 16), x1 = x0 + 15.f;
        const float y0 = (float)(by * 16), y1 = y0 + 15.f;
        #pragma unroll
        for (int gi = 0; gi < 2; ++gi) {
            const int rk = g_rank[gi];
            sortedIdx[rk] = tid + gi * 256;
            const float r = g_r[gi];
            if (r > 0.f &&
                g_px[gi] + r >= x0 && g_px[gi] - r <= x1 &&
                g_py[gi] + r >= y0 && g_py[gi] - r <= y1) {
                atomicOr(&tmask[rk >> 5], 1u << (rk & 31));
            }
        }
    }
    __syncthreads();

    // ---- Phase 2.5: prefix-popcount compaction into sequential LDS arrays
    int nc = 0;
    {
        #pragma unroll
        for (int w = 0; w < N_G / 32; ++w) nc += __popc(tmask[w]);

        #pragma unroll
        for (int gi = 0; gi < 2; ++gi) {
            const int r = tid + gi * 256;
            const unsigned mw = tmask[r >> 5];
            if (mw & (1u << (r & 31))) {
                int pos = __popc(mw & ((1u << (r & 31)) - 1u));
                for (int w = 0; w < (r >> 5); ++w) pos += __popc(tmask[w]);
                const int g = sortedIdx[r];
                c0[pos] = make_float4(sp[0][g], sp[1][g], sp[2][g], sp[3][g]);
                c1[pos] = make_float4(sp[4][g], sp[5][g], sp[6][g], sp[7][g]);
                c2[pos] = sp[8][g];
            }
        }
        const int ncp = (nc + 7) & ~7;
        for (int i = nc + tid; i < ncp; i += 256) {   // NaN-safe pad: al=0 -> skipped
            c0[i] = make_float4(0.f, 0.f, 0.f, 0.f);
            c1[i] = make_float4(0.f, 0.f, 0.f, 0.f);
            c2[i] = 0.f;
        }
    }
    __syncthreads();

    // ---- Phase 3: front-to-back blend over compact list, unrolled x8
    const int lx = tid & 15, ly = tid >> 4;
    const int px = bx * 16 + lx, py = by * 16 + ly;
    const float fx = (float)px, fy = (float)py;

    float T = 1.f, cr = 0.f, cg = 0.f, cb = 0.f;
    bool done = false;
    const int ncp = (nc + 7) & ~7;
    for (int base = 0; base < ncp; base += 8) {
        #pragma unroll
        for (int u = 0; u < 8; ++u) {
            const int i = base + u;
            const float4 p0 = c0[i];
            const float4 p1 = c1[i];
            const float  pb = c2[i];
            const float dx = p0.x - fx;
            const float dy = p0.y - fy;
            const float power = -0.5f*(p0.z*dx*dx + p1.x*dy*dy) - p0.w*dx*dy;
            const float al = fminf(0.99f, p1.y*__expf(power));
            if (!done && !(power > 0.f || al < (1.0f/255.0f))) {
                const float Tnew = T * (1.f - al);
                if (Tnew < 1e-4f) { T = Tnew; done = true; }
                else {
                    const float wgt = al * T;
                    cr += wgt * p1.z;
                    cg += wgt * p1.w;
                    cb += wgt * pb;
                    T = Tnew;
                }
            }
        }
        if (__all(done)) break;
    }
    const int pix = py * IMG_W + px;
    img[pix]                   = cr + T * bg[0];
    img[IMG_H*IMG_W   + pix]   = cg + T * bg[1];
    img[2*IMG_H*IMG_W + pix]   = cb + T * bg[2];
}

extern "C" void kernel_launch(void* const* d_in, const int* in_sizes, int n_in,
                              void* d_out, int out_size, void* d_ws, size_t ws_size,
                              hipStream_t stream) {
    const float* means3D    = (const float*)d_in[0];
    // d_in[1] = means2D (unused by reference math)
    const float* opacities  = (const float*)d_in[2];
    const float* colors     = (const float*)d_in[3];
    const float* scales     = (const float*)d_in[4];
    const float* rotations  = (const float*)d_in[5];
    const float* viewmatrix = (const float*)d_in[6];
    const float* projmatrix = (const float*)d_in[7];
    const float* bg         = (const float*)d_in[8];

    float* img   = (float*)d_out;                   // 3*256*256
    float* radii = (float*)d_out + 3*IMG_H*IMG_W;   // 512 (as float values)

    gs_fused<<<(IMG_H/16)*(IMG_W/16), 256, 0, stream>>>(
        means3D, opacities, colors, scales, rotations,
        viewmatrix, projmatrix, bg, img, radii);
}

// Round 4
// 31.475 us; speedup vs baseline: 3.1378x; 1.4387x over previous
//
#include <hip/hip_runtime.h>
#include <math.h>

#define N_G    512
#define IMG_H  256
#define IMG_W  256

// Kernel A: one block, 512 threads. Preprocess every gaussian once (registers
// only), stable counting-rank by depth (tz), scatter depth-sorted SoA float4
// planes into ws:
//   ws4[r]        = {px, py, conA, conB}
//   ws4[512 + r]  = {conC, op, col_r, col_g}
//   ws4[1024 + r] = {col_b, cull_radius, 0, 0}
__global__ __launch_bounds__(512) void gs_prep(
    const float* __restrict__ means3D,
    const float* __restrict__ opacities,
    const float* __restrict__ colors,
    const float* __restrict__ scales,
    const float* __restrict__ rotations,
    const float* __restrict__ viewmatrix,
    const float* __restrict__ projmatrix,
    float4* __restrict__ ws4,
    float* __restrict__ radii_out)
{
    __shared__ float skey[N_G];
    const int g = threadIdx.x;

    float VM[16], PM[16];
    #pragma unroll
    for (int i = 0; i < 16; ++i) { VM[i] = viewmatrix[i]; PM[i] = projmatrix[i]; }

    const float mx = means3D[g*3+0], my = means3D[g*3+1], mz = means3D[g*3+2];
    float rq = rotations[g*4+0], xq = rotations[g*4+1], yq = rotations[g*4+2], zq = rotations[g*4+3];
    const float qn = sqrtf(rq*rq + xq*xq + yq*yq + zq*zq);
    rq /= qn; xq /= qn; yq /= qn; zq /= qn;
    const float R00 = 1.f - 2.f*(yq*yq + zq*zq);
    const float R01 = 2.f*(xq*yq - rq*zq);
    const float R02 = 2.f*(xq*zq + rq*yq);
    const float R10 = 2.f*(xq*yq + rq*zq);
    const float R11 = 1.f - 2.f*(xq*xq + zq*zq);
    const float R12 = 2.f*(yq*zq - rq*xq);
    const float R20 = 2.f*(xq*zq - rq*yq);
    const float R21 = 2.f*(yq*zq + rq*xq);
    const float R22 = 1.f - 2.f*(xq*xq + yq*yq);
    float s0 = scales[g*3+0], s1 = scales[g*3+1], s2 = scales[g*3+2];
    s0 *= s0; s1 *= s1; s2 *= s2;
    const float S00 = R00*R00*s0 + R01*R01*s1 + R02*R02*s2;
    const float S01 = R00*R10*s0 + R01*R11*s1 + R02*R12*s2;
    const float S02 = R00*R20*s0 + R01*R21*s1 + R02*R22*s2;
    const float S11 = R10*R10*s0 + R11*R11*s1 + R12*R12*s2;
    const float S12 = R10*R20*s0 + R11*R21*s1 + R12*R22*s2;
    const float S22 = R20*R20*s0 + R21*R21*s1 + R22*R22*s2;

    const float pv0 = VM[0]*mx + VM[1]*my + VM[2]*mz  + VM[3];
    const float pv1 = VM[4]*mx + VM[5]*my + VM[6]*mz  + VM[7];
    const float tz  = VM[8]*mx + VM[9]*my + VM[10]*mz + VM[11];
    const float FX = 256.f, FY = 256.f, limx = 0.65f, limy = 0.65f;
    const float tx = fminf(fmaxf(pv0/tz, -limx), limx) * tz;
    const float ty = fminf(fmaxf(pv1/tz, -limy), limy) * tz;
    const float itz = 1.f / tz, itz2 = itz*itz;
    const float J00 = FX*itz, J02 = -FX*tx*itz2;
    const float J11 = FY*itz, J12 = -FY*ty*itz2;
    const float T00 = J00*VM[0] + J02*VM[8];
    const float T01 = J00*VM[1] + J02*VM[9];
    const float T02 = J00*VM[2] + J02*VM[10];
    const float T10 = J11*VM[4] + J12*VM[8];
    const float T11 = J11*VM[5] + J12*VM[9];
    const float T12 = J11*VM[6] + J12*VM[10];
    const float u0 = T00*S00 + T01*S01 + T02*S02;
    const float u1 = T00*S01 + T01*S11 + T02*S12;
    const float u2 = T00*S02 + T01*S12 + T02*S22;
    const float v0 = T10*S00 + T11*S01 + T12*S02;
    const float v1 = T10*S01 + T11*S11 + T12*S12;
    const float v2 = T10*S02 + T11*S12 + T12*S22;
    const float c00 = u0*T00 + u1*T01 + u2*T02;
    const float c01 = u0*T10 + u1*T11 + u2*T12;
    const float c11 = v0*T10 + v1*T11 + v2*T12;
    const float a = c00 + 0.3f, b = c01, c = c11 + 0.3f;
    const float det = a*c - b*b;
    const float inv_det = 1.f/det;
    float conA = c*inv_det, conB = -b*inv_det, conC = a*inv_det;
    const float ph0 = PM[0]*mx  + PM[1]*my  + PM[2]*mz  + PM[3];
    const float ph1 = PM[4]*mx  + PM[5]*my  + PM[6]*mz  + PM[7];
    const float ph3 = PM[12]*mx + PM[13]*my + PM[14]*mz + PM[15];
    const float pw = 1.f/(ph3 + 1e-7f);
    const float pix_x = ((ph0*pw + 1.f)*(float)IMG_W - 1.f)*0.5f;
    const float pix_y = ((ph1*pw + 1.f)*(float)IMG_H - 1.f)*0.5f;
    const float mid = 0.5f*(a + c);
    const float lam = mid + sqrtf(fmaxf(0.1f, mid*mid - det));
    const bool valid = (tz > 0.2f) && (det > 0.f);
    float op = opacities[g];
    if (!valid) { conA = conB = conC = 0.f; op = 0.f; }

    radii_out[g] = valid ? ceilf(3.f*sqrtf(lam)) : 0.f;

    // Conservative cull radius: contribution needs op*exp(-|d|^2/(2*lam)) >= 1/255
    // => |d|^2 <= 2*lam*ln(255*op); lam >= lambda_max since sqrt arg clamped up.
    const bool cullable = valid && (op * 255.f > 1.f);
    const float crad = cullable ? sqrtf(2.f * lam * logf(255.f * op)) + 0.01f : -1.f;

    skey[g] = tz;
    __syncthreads();

    // Stable counting-rank on (tz, idx) — matches jnp.argsort(tz) (stable asc)
    int rk = 0;
    #pragma unroll 16
    for (int j = 0; j < N_G; ++j) {
        const float kj = skey[j];                 // LDS broadcast
        rk += (kj < tz) || (kj == tz && j < g);
    }

    ws4[rk]           = make_float4(pix_x, pix_y, conA, conB);
    ws4[N_G + rk]     = make_float4(conC, op, colors[g*3+0], colors[g*3+1]);
    ws4[2*N_G + rk]   = make_float4(colors[g*3+2], crad, 0.f, 0.f);
}

// Kernel B: one block per 16x16 tile. Scan the precomputed depth-sorted list,
// build coverage bitmask (rank-indexed), popcount-compact into LDS, blend.
__global__ __launch_bounds__(256) void gs_raster(
    const float4* __restrict__ ws4,
    const float* __restrict__ bg,
    float* __restrict__ img)
{
    __shared__ unsigned tmask[N_G / 32];
    __shared__ float4 c0[N_G];          // {px,py,A,B}
    __shared__ float4 c1[N_G];          // {C,op,cr,cg}
    __shared__ float  c2[N_G];          // {cb}

    const int tid = threadIdx.x;
    const int bx = blockIdx.x & 15, by = blockIdx.x >> 4;

    if (tid < N_G / 32) tmask[tid] = 0u;
    __syncthreads();

    const float x0 = (float)(bx * 16), x1 = x0 + 15.f;
    const float y0 = (float)(by * 16), y1 = y0 + 15.f;

    // scan: 2 gaussians per thread (coalesced float4 loads)
    #pragma unroll
    for (int gi = 0; gi < 2; ++gi) {
        const int r = tid + gi * 256;
        const float4 w0 = ws4[r];            // px,py,A,B
        const float4 w2 = ws4[2*N_G + r];    // cb,rad
        const float rad = w2.y;
        if (rad > 0.f &&
            w0.x + rad >= x0 && w0.x - rad <= x1 &&
            w0.y + rad >= y0 && w0.y - rad <= y1) {
            atomicOr(&tmask[r >> 5], 1u << (r & 31));
        }
    }
    __syncthreads();

    int nc = 0;
    #pragma unroll
    for (int w = 0; w < N_G / 32; ++w) nc += __popc(tmask[w]);

    // compact covering gaussians (already depth-ordered by rank)
    #pragma unroll
    for (int gi = 0; gi < 2; ++gi) {
        const int r = tid + gi * 256;
        const unsigned mw = tmask[r >> 5];
        if (mw & (1u << (r & 31))) {
            int pos = __popc(mw & ((1u << (r & 31)) - 1u));
            for (int w = 0; w < (r >> 5); ++w) pos += __popc(tmask[w]);
            const float4 w2 = ws4[2*N_G + r];
            c0[pos] = ws4[r];
            c1[pos] = ws4[N_G + r];
            c2[pos] = w2.x;
        }
    }
    const int ncp = (nc + 7) & ~7;
    for (int i = nc + tid; i < ncp; i += 256) {   // NaN-safe pad: al=0 -> skipped
        c0[i] = make_float4(0.f, 0.f, 0.f, 0.f);
        c1[i] = make_float4(0.f, 0.f, 0.f, 0.f);
        c2[i] = 0.f;
    }
    __syncthreads();

    // front-to-back blend, unrolled x8
    const int lx = tid & 15, ly = tid >> 4;
    const int px = bx * 16 + lx, py = by * 16 + ly;
    const float fx = (float)px, fy = (float)py;

    float T = 1.f, cr = 0.f, cg = 0.f, cb = 0.f;
    bool done = false;
    for (int base = 0; base < ncp; base += 8) {
        #pragma unroll
        for (int u = 0; u < 8; ++u) {
            const int i = base + u;
            const float4 p0 = c0[i];
            const float4 p1 = c1[i];
            const float  pb = c2[i];
            const float dx = p0.x - fx;
            const float dy = p0.y - fy;
            const float power = -0.5f*(p0.z*dx*dx + p1.x*dy*dy) - p0.w*dx*dy;
            const float al = fminf(0.99f, p1.y*__expf(power));
            if (!done && !(power > 0.f || al < (1.0f/255.0f))) {
                const float Tnew = T * (1.f - al);
                if (Tnew < 1e-4f) { T = Tnew; done = true; }
                else {
                    const float wgt = al * T;
                    cr += wgt * p1.z;
                    cg += wgt * p1.w;
                    cb += wgt * pb;
                    T = Tnew;
                }
            }
        }
        if (__all(done)) break;
    }
    const int pix = py * IMG_W + px;
    img[pix]                   = cr + T * bg[0];
    img[IMG_H*IMG_W   + pix]   = cg + T * bg[1];
    img[2*IMG_H*IMG_W + pix]   = cb + T * bg[2];
}

extern "C" void kernel_launch(void* const* d_in, const int* in_sizes, int n_in,
                              void* d_out, int out_size, void* d_ws, size_t ws_size,
                              hipStream_t stream) {
    const float* means3D    = (const float*)d_in[0];
    // d_in[1] = means2D (unused by reference math)
    const float* opacities  = (const float*)d_in[2];
    const float* colors     = (const float*)d_in[3];
    const float* scales     = (const float*)d_in[4];
    const float* rotations  = (const float*)d_in[5];
    const float* viewmatrix = (const float*)d_in[6];
    const float* projmatrix = (const float*)d_in[7];
    const float* bg         = (const float*)d_in[8];

    float* img   = (float*)d_out;                   // 3*256*256
    float* radii = (float*)d_out + 3*IMG_H*IMG_W;   // 512 (as float values)
    float4* ws4  = (float4*)d_ws;                   // 3*512 float4

    gs_prep<<<1, N_G, 0, stream>>>(means3D, opacities, colors, scales,
                                   rotations, viewmatrix, projmatrix, ws4, radii);
    gs_raster<<<(IMG_H/16)*(IMG_W/16), 256, 0, stream>>>(ws4, bg, img);
}

// Round 5
// 18.044 us; speedup vs baseline: 5.4735x; 1.7444x over previous
//
#include <hip/hip_runtime.h>
#include <math.h>

#define N_G    512
#define IMG_H  256
#define IMG_W  256

// Kernel A: 8 blocks x 64 threads, one gaussian per thread, registers only.
// Writes ORIGINAL-ORDER SoA planes (no global sort — depth ordering is done
// per-tile in kernel B over the tiny covering subset):
//   g0[g] = {px, py, cull_rad, tz}     (cull_rad = -1 -> never renders)
//   g1[g] = {conA, conB, conC, op}
//   g2[g] = {col_r, col_g, col_b, 0}
__global__ __launch_bounds__(64) void gs_prep(
    const float* __restrict__ means3D,
    const float* __restrict__ opacities,
    const float* __restrict__ colors,
    const float* __restrict__ scales,
    const float* __restrict__ rotations,
    const float* __restrict__ viewmatrix,
    const float* __restrict__ projmatrix,
    float4* __restrict__ g0,
    float4* __restrict__ g1,
    float4* __restrict__ g2,
    float* __restrict__ radii_out)
{
    const int g = blockIdx.x * 64 + threadIdx.x;

    float VM[16], PM[16];
    #pragma unroll
    for (int i = 0; i < 16; ++i) { VM[i] = viewmatrix[i]; PM[i] = projmatrix[i]; }

    const float mx = means3D[g*3+0], my = means3D[g*3+1], mz = means3D[g*3+2];
    float rq = rotations[g*4+0], xq = rotations[g*4+1], yq = rotations[g*4+2], zq = rotations[g*4+3];
    const float qn = sqrtf(rq*rq + xq*xq + yq*yq + zq*zq);
    rq /= qn; xq /= qn; yq /= qn; zq /= qn;
    const float R00 = 1.f - 2.f*(yq*yq + zq*zq);
    const float R01 = 2.f*(xq*yq - rq*zq);
    const float R02 = 2.f*(xq*zq + rq*yq);
    const float R10 = 2.f*(xq*yq + rq*zq);
    const float R11 = 1.f - 2.f*(xq*xq + zq*zq);
    const float R12 = 2.f*(yq*zq - rq*xq);
    const float R20 = 2.f*(xq*zq - rq*yq);
    const float R21 = 2.f*(yq*zq + rq*xq);
    const float R22 = 1.f - 2.f*(xq*xq + yq*yq);
    float s0 = scales[g*3+0], s1 = scales[g*3+1], s2 = scales[g*3+2];
    s0 *= s0; s1 *= s1; s2 *= s2;
    const float S00 = R00*R00*s0 + R01*R01*s1 + R02*R02*s2;
    const float S01 = R00*R10*s0 + R01*R11*s1 + R02*R12*s2;
    const float S02 = R00*R20*s0 + R01*R21*s1 + R02*R22*s2;
    const float S11 = R10*R10*s0 + R11*R11*s1 + R12*R12*s2;
    const float S12 = R10*R20*s0 + R11*R21*s1 + R12*R22*s2;
    const float S22 = R20*R20*s0 + R21*R21*s1 + R22*R22*s2;

    const float pv0 = VM[0]*mx + VM[1]*my + VM[2]*mz  + VM[3];
    const float pv1 = VM[4]*mx + VM[5]*my + VM[6]*mz  + VM[7];
    const float tz  = VM[8]*mx + VM[9]*my + VM[10]*mz + VM[11];
    const float FX = 256.f, FY = 256.f, limx = 0.65f, limy = 0.65f;
    const float tx = fminf(fmaxf(pv0/tz, -limx), limx) * tz;
    const float ty = fminf(fmaxf(pv1/tz, -limy), limy) * tz;
    const float itz = 1.f / tz, itz2 = itz*itz;
    const float J00 = FX*itz, J02 = -FX*tx*itz2;
    const float J11 = FY*itz, J12 = -FY*ty*itz2;
    const float T00 = J00*VM[0] + J02*VM[8];
    const float T01 = J00*VM[1] + J02*VM[9];
    const float T02 = J00*VM[2] + J02*VM[10];
    const float T10 = J11*VM[4] + J12*VM[8];
    const float T11 = J11*VM[5] + J12*VM[9];
    const float T12 = J11*VM[6] + J12*VM[10];
    const float u0 = T00*S00 + T01*S01 + T02*S02;
    const float u1 = T00*S01 + T01*S11 + T02*S12;
    const float u2 = T00*S02 + T01*S12 + T02*S22;
    const float v0 = T10*S00 + T11*S01 + T12*S02;
    const float v1 = T10*S01 + T11*S11 + T12*S12;
    const float v2 = T10*S02 + T11*S12 + T12*S22;
    const float c00 = u0*T00 + u1*T01 + u2*T02;
    const float c01 = u0*T10 + u1*T11 + u2*T12;
    const float c11 = v0*T10 + v1*T11 + v2*T12;
    const float a = c00 + 0.3f, b = c01, c = c11 + 0.3f;
    const float det = a*c - b*b;
    const float inv_det = 1.f/det;
    float conA = c*inv_det, conB = -b*inv_det, conC = a*inv_det;
    const float ph0 = PM[0]*mx  + PM[1]*my  + PM[2]*mz  + PM[3];
    const float ph1 = PM[4]*mx  + PM[5]*my  + PM[6]*mz  + PM[7];
    const float ph3 = PM[12]*mx + PM[13]*my + PM[14]*mz + PM[15];
    const float pw = 1.f/(ph3 + 1e-7f);
    const float pix_x = ((ph0*pw + 1.f)*(float)IMG_W - 1.f)*0.5f;
    const float pix_y = ((ph1*pw + 1.f)*(float)IMG_H - 1.f)*0.5f;
    const float mid = 0.5f*(a + c);
    const float lam = mid + sqrtf(fmaxf(0.1f, mid*mid - det));
    const bool valid = (tz > 0.2f) && (det > 0.f);
    float op = opacities[g];
    if (!valid) { conA = conB = conC = 0.f; op = 0.f; }

    radii_out[g] = valid ? ceilf(3.f*sqrtf(lam)) : 0.f;

    // Conservative cull radius: al >= 1/255 needs |d|^2 <= 2*lam*ln(255*op)
    // (lam >= lambda_max of regularized cov2d since the sqrt arg is clamped up).
    float rad = -1.f;
    if (valid && op * 255.f > 1.f) {
        const float r = sqrtf(2.f * lam * logf(255.f * op)) + 0.01f;
        // whole-image cull: bbox must intersect [0,255]^2
        if (pix_x + r >= 0.f && pix_x - r <= (float)(IMG_W-1) &&
            pix_y + r >= 0.f && pix_y - r <= (float)(IMG_H-1))
            rad = r;
    }

    g0[g] = make_float4(pix_x, pix_y, rad, tz);
    g1[g] = make_float4(conA, conB, conC, op);
    g2[g] = make_float4(colors[g*3+0], colors[g*3+1], colors[g*3+2], 0.f);
}

// Kernel B: 512 blocks x 128 threads, one 16x8 tile per block (2 blocks/CU).
// scan(coalesced float4) -> LDS append -> local stable rank by (tz, idx)
// (== global stable argsort restricted to the covering subset) -> blend.
__global__ __launch_bounds__(128) void gs_raster(
    const float4* __restrict__ g0,
    const float4* __restrict__ g1,
    const float4* __restrict__ g2,
    const float* __restrict__ bg,
    float* __restrict__ img)
{
    __shared__ int   s_n;
    __shared__ float s_tz[N_G];
    __shared__ int   s_id[N_G];
    __shared__ float4 c0[N_G];          // {px,py,A,B}  depth-ordered
    __shared__ float4 c1[N_G];          // {C,op,cr,cg}
    __shared__ float  c2[N_G];          // {cb}

    const int tid = threadIdx.x;
    if (tid == 0) s_n = 0;
    __syncthreads();

    const int bx = blockIdx.x & 15, by = blockIdx.x >> 4;   // 16 x 32 tiles of 16x8
    const float x0 = (float)(bx * 16), x1 = x0 + 15.f;
    const float y0 = (float)(by * 8),  y1 = y0 + 7.f;

    // scan all gaussians: 4 per thread, coalesced 16B loads
    #pragma unroll
    for (int gi = 0; gi < 4; ++gi) {
        const int g = tid + gi * 128;
        const float4 w = g0[g];
        if (w.z > 0.f &&
            w.x + w.z >= x0 && w.x - w.z <= x1 &&
            w.y + w.z >= y0 && w.y - w.z <= y1) {
            const int p = atomicAdd(&s_n, 1);
            s_tz[p] = w.w;
            s_id[p] = g;
        }
    }
    __syncthreads();

    const int nc  = s_n;
    const int ncp = (nc + 7) & ~7;

    // local stable rank by (tz, original idx) + gather params into ranked slots
    for (int i = tid; i < nc; i += 128) {
        const float tz = s_tz[i];
        const int   id = s_id[i];
        int r = 0;
        #pragma unroll 8
        for (int j = 0; j < nc; ++j) {
            const float tj = s_tz[j];
            r += (tj < tz) || (tj == tz && s_id[j] < id);
        }
        const float4 a0 = g0[id];   // L2-resident scattered reads
        const float4 a1 = g1[id];
        const float4 a2 = g2[id];
        c0[r] = make_float4(a0.x, a0.y, a1.x, a1.y);
        c1[r] = make_float4(a1.z, a1.w, a2.x, a2.y);
        c2[r] = a2.z;
    }
    for (int i = nc + tid; i < ncp; i += 128) {  // zero pad: al=0 -> skipped, no NaN
        c0[i] = make_float4(0.f, 0.f, 0.f, 0.f);
        c1[i] = make_float4(0.f, 0.f, 0.f, 0.f);
        c2[i] = 0.f;
    }
    __syncthreads();

    // front-to-back blend, one pixel per thread, unrolled x8
    const int lx = tid & 15, ly = tid >> 4;
    const int px = bx * 16 + lx, py = by * 8 + ly;
    const float fx = (float)px, fy = (float)py;

    float T = 1.f, cr = 0.f, cg = 0.f, cb = 0.f;
    bool done = false;
    for (int base = 0; base < ncp; base += 8) {
        #pragma unroll
        for (int u = 0; u < 8; ++u) {
            const int i = base + u;
            const float4 p0 = c0[i];
            const float4 p1 = c1[i];
            const float  pb = c2[i];
            const float dx = p0.x - fx;
            const float dy = p0.y - fy;
            const float power = -0.5f*(p0.z*dx*dx + p1.x*dy*dy) - p0.w*dx*dy;
            const float al = fminf(0.99f, p1.y*__expf(power));
            if (!done && !(power > 0.f || al < (1.0f/255.0f))) {
                const float Tnew = T * (1.f - al);
                if (Tnew < 1e-4f) { T = Tnew; done = true; }
                else {
                    const float wgt = al * T;
                    cr += wgt * p1.z;
                    cg += wgt * p1.w;
                    cb += wgt * pb;
                    T = Tnew;
                }
            }
        }
        if (__all(done)) break;
    }
    const int pix = py * IMG_W + px;
    img[pix]                   = cr + T * bg[0];
    img[IMG_H*IMG_W   + pix]   = cg + T * bg[1];
    img[2*IMG_H*IMG_W + pix]   = cb + T * bg[2];
}

extern "C" void kernel_launch(void* const* d_in, const int* in_sizes, int n_in,
                              void* d_out, int out_size, void* d_ws, size_t ws_size,
                              hipStream_t stream) {
    const float* means3D    = (const float*)d_in[0];
    // d_in[1] = means2D (unused by reference math)
    const float* opacities  = (const float*)d_in[2];
    const float* colors     = (const float*)d_in[3];
    const float* scales     = (const float*)d_in[4];
    const float* rotations  = (const float*)d_in[5];
    const float* viewmatrix = (const float*)d_in[6];
    const float* projmatrix = (const float*)d_in[7];
    const float* bg         = (const float*)d_in[8];

    float* img   = (float*)d_out;                   // 3*256*256
    float* radii = (float*)d_out + 3*IMG_H*IMG_W;   // 512 (as float values)
    float4* g0   = (float4*)d_ws;                   // 512 float4
    float4* g1   = g0 + N_G;
    float4* g2   = g1 + N_G;

    gs_prep<<<8, 64, 0, stream>>>(means3D, opacities, colors, scales,
                                  rotations, viewmatrix, projmatrix,
                                  g0, g1, g2, radii);
    gs_raster<<<(IMG_W/16)*(IMG_H/8), 128, 0, stream>>>(g0, g1, g2, bg, img);
}